// Round 1
// baseline (140.302 us; speedup 1.0000x reference)
//
#include <hip/hip_runtime.h>

#define BLK 256
#define IPT 8          // i-points per thread (register tile)
#define JTILE 128      // j-points per LDS tile / per blockIdx.y

// Kernel 1: build combined (center, signed-normal) array.
// Layout: comb[2*i]   = (cx, cy, cz, nx)
//         comb[2*i+1] = (ny, nz, 0, 0)
// i in [0,N): triangle centers/normals from gathered vertices.
// i in [N,N+M): target centers, NEGATED target normals (sign trick folds
// e_ss - 2 e_st + e_tt into one pairwise sum).
__global__ void dc_build_combined(const float* __restrict__ verts,
                                  const float* __restrict__ tnorm,
                                  const float* __restrict__ tcent,
                                  const int* __restrict__ idx,
                                  float4* __restrict__ comb,
                                  int N, int M) {
    int i = blockIdx.x * blockDim.x + threadIdx.x;
    int P = N + M;
    if (i >= P) return;
    if (i < N) {
        int i0 = idx[3 * i + 0];
        int i1 = idx[3 * i + 1];
        int i2 = idx[3 * i + 2];
        float ax = verts[3 * i0 + 0], ay = verts[3 * i0 + 1], az = verts[3 * i0 + 2];
        float bx = verts[3 * i1 + 0], by = verts[3 * i1 + 1], bz = verts[3 * i1 + 2];
        float cx = verts[3 * i2 + 0], cy = verts[3 * i2 + 1], cz = verts[3 * i2 + 2];
        // normals = 0.5 * cross(a - b, c - b)
        float ux = ax - bx, uy = ay - by, uz = az - bz;
        float vx = cx - bx, vy = cy - by, vz = cz - bz;
        float nx = 0.5f * (uy * vz - uz * vy);
        float ny = 0.5f * (uz * vx - ux * vz);
        float nz = 0.5f * (ux * vy - uy * vx);
        // centers = (a + b + c) / 3
        float gx = (ax + bx + cx) * (1.0f / 3.0f);
        float gy = (ay + by + cy) * (1.0f / 3.0f);
        float gz = (az + bz + cz) * (1.0f / 3.0f);
        comb[2 * i + 0] = make_float4(gx, gy, gz, nx);
        comb[2 * i + 1] = make_float4(ny, nz, 0.0f, 0.0f);
    } else {
        int t = i - N;
        float tx = tcent[3 * t + 0], ty = tcent[3 * t + 1], tz = tcent[3 * t + 2];
        float nx = -tnorm[3 * t + 0], ny = -tnorm[3 * t + 1], nz = -tnorm[3 * t + 2];
        comb[2 * i + 0] = make_float4(tx, ty, tz, nx);
        comb[2 * i + 1] = make_float4(ny, nz, 0.0f, 0.0f);
    }
}

// Kernel 2: E = sum_{i,j} <n_i, n_j> / (1 + |c_i - c_j|^2)   (SIGMA = 1)
// Each thread owns IPT i-points in registers; j staged in LDS (broadcast
// reads, conflict-free). Grid: (P/(BLK*IPT), P/JTILE).
__global__ __launch_bounds__(BLK, 4) void dc_pair_energy(
    const float4* __restrict__ comb, float* __restrict__ out, int P) {
    __shared__ float4 tile[2 * JTILE];
    __shared__ float wsum[BLK / 64];

    int tid = threadIdx.x;
    int ibase = blockIdx.x * (BLK * IPT);

    float4 A[IPT], B[IPT];
#pragma unroll
    for (int k = 0; k < IPT; ++k) {
        int i = ibase + k * BLK + tid;
        if (i < P) {
            A[k] = comb[2 * i + 0];
            B[k] = comb[2 * i + 1];
        } else {
            A[k] = make_float4(0.f, 0.f, 0.f, 0.f);
            B[k] = make_float4(0.f, 0.f, 0.f, 0.f);
        }
    }
    float acc[IPT];
#pragma unroll
    for (int k = 0; k < IPT; ++k) acc[k] = 0.0f;

    // stage j-tile into LDS (coalesced)
    int j0 = blockIdx.y * JTILE;
    for (int s = tid; s < 2 * JTILE; s += BLK) {
        int gidx = 2 * j0 + s;
        tile[s] = (gidx < 2 * P) ? comb[gidx] : make_float4(0.f, 0.f, 0.f, 0.f);
    }
    __syncthreads();

#pragma unroll 2
    for (int jj = 0; jj < JTILE; ++jj) {
        float4 a = tile[2 * jj + 0];   // cjx, cjy, cjz, njx  (broadcast)
        float4 b = tile[2 * jj + 1];   // njy, njz, -, -
#pragma unroll
        for (int k = 0; k < IPT; ++k) {
            float dx = A[k].x - a.x;
            float dy = A[k].y - a.y;
            float dz = A[k].z - a.z;
            float d2p = fmaf(dx, dx, fmaf(dy, dy, fmaf(dz, dz, 1.0f)));
            float rk = __builtin_amdgcn_rcpf(d2p);
            float dot = fmaf(A[k].w, a.w, fmaf(B[k].x, b.x, B[k].y * b.y));
            acc[k] = fmaf(rk, dot, acc[k]);
        }
    }

    // per-thread -> wave -> block reduction
    float s = 0.0f;
#pragma unroll
    for (int k = 0; k < IPT; ++k) s += acc[k];
#pragma unroll
    for (int off = 32; off > 0; off >>= 1) s += __shfl_down(s, off, 64);
    if ((tid & 63) == 0) wsum[tid >> 6] = s;
    __syncthreads();
    if (tid == 0) {
        float t = 0.0f;
#pragma unroll
        for (int w = 0; w < BLK / 64; ++w) t += wsum[w];
        atomicAdd(out, t);
    }
}

extern "C" void kernel_launch(void* const* d_in, const int* in_sizes, int n_in,
                              void* d_out, int out_size, void* d_ws, size_t ws_size,
                              hipStream_t stream) {
    const float* verts = (const float*)d_in[0];   // (V,3) f32
    const float* tnorm = (const float*)d_in[1];   // (M,3) f32
    const float* tcent = (const float*)d_in[2];   // (M,3) f32
    const int*   sidx  = (const int*)d_in[3];     // (N,3) i32

    int M = in_sizes[1] / 3;
    int N = in_sizes[3] / 3;
    int P = N + M;                                // 16384

    float4* comb = (float4*)d_ws;                 // 2 float4 per point = 512 KB
    float*  out  = (float*)d_out;

    // d_out is poisoned before every call -- zero it in-stream.
    hipMemsetAsync(out, 0, sizeof(float), stream);

    int bblocks = (P + BLK - 1) / BLK;
    dc_build_combined<<<bblocks, BLK, 0, stream>>>(verts, tnorm, tcent, sidx, comb, N, M);

    dim3 grid((P + BLK * IPT - 1) / (BLK * IPT), (P + JTILE - 1) / JTILE);
    dc_pair_energy<<<grid, BLK, 0, stream>>>(comb, out, P);
}

// Round 2
// 133.485 us; speedup vs baseline: 1.0511x; 1.0511x over previous
//
#include <hip/hip_runtime.h>

#define BLK 256
#define IPT 4                      // i-points per thread
#define ITILE (BLK * IPT)          // 1024 i-points per block-row
#define JTILE 128                  // j-points per LDS tile

// Kernel 1: build combined (center, signed-normal) array; also zero d_out.
// comb[2*i] = (cx,cy,cz,nx); comb[2*i+1] = (ny,nz,0,0).
// i in [N,N+M): target centers with NEGATED normals, so
// e_ss - 2 e_st + e_tt = sum over all pairs of the combined set.
__global__ void dc_build_combined(const float* __restrict__ verts,
                                  const float* __restrict__ tnorm,
                                  const float* __restrict__ tcent,
                                  const int* __restrict__ idx,
                                  float4* __restrict__ comb,
                                  float* __restrict__ out,
                                  int N, int M) {
    int i = blockIdx.x * blockDim.x + threadIdx.x;
    if (i == 0) out[0] = 0.0f;     // replaces hipMemsetAsync dispatch
    int P = N + M;
    if (i >= P) return;
    if (i < N) {
        int i0 = idx[3 * i + 0];
        int i1 = idx[3 * i + 1];
        int i2 = idx[3 * i + 2];
        float ax = verts[3 * i0 + 0], ay = verts[3 * i0 + 1], az = verts[3 * i0 + 2];
        float bx = verts[3 * i1 + 0], by = verts[3 * i1 + 1], bz = verts[3 * i1 + 2];
        float cx = verts[3 * i2 + 0], cy = verts[3 * i2 + 1], cz = verts[3 * i2 + 2];
        float ux = ax - bx, uy = ay - by, uz = az - bz;
        float vx = cx - bx, vy = cy - by, vz = cz - bz;
        float nx = 0.5f * (uy * vz - uz * vy);
        float ny = 0.5f * (uz * vx - ux * vz);
        float nz = 0.5f * (ux * vy - uy * vx);
        float gx = (ax + bx + cx) * (1.0f / 3.0f);
        float gy = (ay + by + cy) * (1.0f / 3.0f);
        float gz = (az + bz + cz) * (1.0f / 3.0f);
        comb[2 * i + 0] = make_float4(gx, gy, gz, nx);
        comb[2 * i + 1] = make_float4(ny, nz, 0.0f, 0.0f);
    } else {
        int t = i - N;
        float tx = tcent[3 * t + 0], ty = tcent[3 * t + 1], tz = tcent[3 * t + 2];
        float nx = -tnorm[3 * t + 0], ny = -tnorm[3 * t + 1], nz = -tnorm[3 * t + 2];
        comb[2 * i + 0] = make_float4(tx, ty, tz, nx);
        comb[2 * i + 1] = make_float4(ny, nz, 0.0f, 0.0f);
    }
}

// Kernel 2: E = sum_{i,j} <n_i,n_j> / (1 + |c_i - c_j|^2), exploiting symmetry:
// skip j-tiles strictly below the i-tile; weight 2 for tiles strictly above
// the diagonal super-tile; weight 1 inside it (computed fully).
__global__ __launch_bounds__(BLK, 4) void dc_pair_energy(
    const float4* __restrict__ comb, float* __restrict__ out, int P) {
    __shared__ float4 tile[2 * JTILE];
    __shared__ float wsum[BLK / 64];

    int tid = threadIdx.x;
    int ibase = blockIdx.x * ITILE;
    int j0 = blockIdx.y * JTILE;

    if (j0 < ibase) return;                          // below diagonal: transpose covers it
    float weight = (j0 >= ibase + ITILE) ? 2.0f : 1.0f;

    float4 A[IPT];
    float2 Bn[IPT];
#pragma unroll
    for (int k = 0; k < IPT; ++k) {
        int i = ibase + k * BLK + tid;
        if (i < P) {
            A[k] = comb[2 * i + 0];
            float4 b = comb[2 * i + 1];
            Bn[k] = make_float2(b.x, b.y);
        } else {
            A[k] = make_float4(0.f, 0.f, 0.f, 0.f);
            Bn[k] = make_float2(0.f, 0.f);
        }
    }
    float acc[IPT];
#pragma unroll
    for (int k = 0; k < IPT; ++k) acc[k] = 0.0f;

    for (int s = tid; s < 2 * JTILE; s += BLK) {
        int gidx = 2 * j0 + s;
        tile[s] = (gidx < 2 * P) ? comb[gidx] : make_float4(0.f, 0.f, 0.f, 0.f);
    }
    __syncthreads();

#pragma unroll 2
    for (int jj = 0; jj < JTILE; ++jj) {
        float4 a = tile[2 * jj + 0];   // cjx,cjy,cjz,njx (broadcast reads)
        float4 b = tile[2 * jj + 1];   // njy,njz,-,-
#pragma unroll
        for (int k = 0; k < IPT; ++k) {
            float dx = A[k].x - a.x;
            float dy = A[k].y - a.y;
            float dz = A[k].z - a.z;
            float d2p = fmaf(dx, dx, fmaf(dy, dy, fmaf(dz, dz, 1.0f)));
            float rk = __builtin_amdgcn_rcpf(d2p);
            float dot = fmaf(A[k].w, a.w, fmaf(Bn[k].x, b.x, Bn[k].y * b.y));
            acc[k] = fmaf(rk, dot, acc[k]);
        }
    }

    float s = 0.0f;
#pragma unroll
    for (int k = 0; k < IPT; ++k) s += acc[k];
    s *= weight;
#pragma unroll
    for (int off = 32; off > 0; off >>= 1) s += __shfl_down(s, off, 64);
    if ((tid & 63) == 0) wsum[tid >> 6] = s;
    __syncthreads();
    if (tid == 0) {
        float t = 0.0f;
#pragma unroll
        for (int w = 0; w < BLK / 64; ++w) t += wsum[w];
        atomicAdd(out, t);
    }
}

extern "C" void kernel_launch(void* const* d_in, const int* in_sizes, int n_in,
                              void* d_out, int out_size, void* d_ws, size_t ws_size,
                              hipStream_t stream) {
    const float* verts = (const float*)d_in[0];   // (V,3) f32
    const float* tnorm = (const float*)d_in[1];   // (M,3) f32
    const float* tcent = (const float*)d_in[2];   // (M,3) f32
    const int*   sidx  = (const int*)d_in[3];     // (N,3) i32

    int M = in_sizes[1] / 3;
    int N = in_sizes[3] / 3;
    int P = N + M;                                // 16384

    float4* comb = (float4*)d_ws;                 // 2 float4/point = 512 KB
    float*  out  = (float*)d_out;

    int bblocks = (P + BLK - 1) / BLK;
    dc_build_combined<<<bblocks, BLK, 0, stream>>>(verts, tnorm, tcent, sidx,
                                                   comb, out, N, M);

    dim3 grid((P + ITILE - 1) / ITILE, (P + JTILE - 1) / JTILE);
    dc_pair_energy<<<grid, BLK, 0, stream>>>(comb, out, P);
}

// Round 3
// 107.958 us; speedup vs baseline: 1.2996x; 1.2364x over previous
//
#include <hip/hip_runtime.h>

#define BLK 256
#define IPT 2                      // i-points per thread
#define ITILE (BLK * IPT)          // 512 i-points per block-row
#define JS 136                     // j-points per slice (64 slices * 136 = 8704 = P/2 + ITILE)

// Kernel 1: build combined (center, signed-normal) array; also zero d_out.
// comb[2*i] = (cx,cy,cz,nx); comb[2*i+1] = (ny,nz,0,0).
// Targets carry NEGATED normals so e_ss - 2 e_st + e_tt = one pairwise sum.
__global__ void dc_build_combined(const float* __restrict__ verts,
                                  const float* __restrict__ tnorm,
                                  const float* __restrict__ tcent,
                                  const int* __restrict__ idx,
                                  float4* __restrict__ comb,
                                  float* __restrict__ out,
                                  int N, int M) {
    int i = blockIdx.x * blockDim.x + threadIdx.x;
    if (i == 0) out[0] = 0.0f;
    int P = N + M;
    if (i >= P) return;
    if (i < N) {
        int i0 = idx[3 * i + 0];
        int i1 = idx[3 * i + 1];
        int i2 = idx[3 * i + 2];
        float ax = verts[3 * i0 + 0], ay = verts[3 * i0 + 1], az = verts[3 * i0 + 2];
        float bx = verts[3 * i1 + 0], by = verts[3 * i1 + 1], bz = verts[3 * i1 + 2];
        float cx = verts[3 * i2 + 0], cy = verts[3 * i2 + 1], cz = verts[3 * i2 + 2];
        float ux = ax - bx, uy = ay - by, uz = az - bz;
        float vx = cx - bx, vy = cy - by, vz = cz - bz;
        float nx = 0.5f * (uy * vz - uz * vy);
        float ny = 0.5f * (uz * vx - ux * vz);
        float nz = 0.5f * (ux * vy - uy * vx);
        float gx = (ax + bx + cx) * (1.0f / 3.0f);
        float gy = (ay + by + cy) * (1.0f / 3.0f);
        float gz = (az + bz + cz) * (1.0f / 3.0f);
        comb[2 * i + 0] = make_float4(gx, gy, gz, nx);
        comb[2 * i + 1] = make_float4(ny, nz, 0.0f, 0.0f);
    } else {
        int t = i - N;
        float tx = tcent[3 * t + 0], ty = tcent[3 * t + 1], tz = tcent[3 * t + 2];
        float nx = -tnorm[3 * t + 0], ny = -tnorm[3 * t + 1], nz = -tnorm[3 * t + 2];
        comb[2 * i + 0] = make_float4(tx, ty, tz, nx);
        comb[2 * i + 1] = make_float4(ny, nz, 0.0f, 0.0f);
    }
}

// Kernel 2: circular half-range symmetric sum.
// For each i: sum over raw offsets cj in [0, P/2 + ITILE) relative to the
// block's i0; pair distance d = cj - (i - i0); weight w(0)=1, w(1..P/2-1)=2,
// w(P/2)=1, else 0. Every block has IDENTICAL work -> zero tail.
// grid = (P/ITILE) x ceil((P/2 + ITILE)/JS) = 32 x 64 = 2048 uniform blocks.
__global__ __launch_bounds__(BLK, 8) void dc_pair_energy(
    const float4* __restrict__ comb, float* __restrict__ out, int P) {
    __shared__ float4 tile[2 * JS];
    __shared__ float wsum[BLK / 64];

    int tid = threadIdx.x;
    int i0 = blockIdx.x * ITILE;
    int half = P >> 1;
    int cj0 = blockIdx.y * JS;                 // first raw offset of this slice
    // interior slice: every (i,j) pair in it has d in [1, half-1] -> weight 2
    bool pure = (cj0 >= ITILE) && (cj0 + JS - 1 <= half - 1);

    // i-points in registers (always in-range: P % ITILE == 0)
    float4 A[IPT];
    float2 Bn[IPT];
    int    li[IPT];
#pragma unroll
    for (int k = 0; k < IPT; ++k) {
        li[k] = k * BLK + tid;
        int i = i0 + li[k];
        A[k] = comb[2 * i + 0];
        float4 b = comb[2 * i + 1];
        Bn[k] = make_float2(b.x, b.y);
    }
    float acc[IPT];
#pragma unroll
    for (int k = 0; k < IPT; ++k) acc[k] = 0.0f;

    // stage j-slice into LDS (wrap mod P; P fits twice so one cond-sub works)
    for (int s = tid; s < 2 * JS; s += BLK) {
        int p  = s >> 1;
        int jr = i0 + cj0 + p;
        int jm = (jr >= P) ? jr - P : jr;
        tile[s] = comb[2 * jm + (s & 1)];
    }
    __syncthreads();

    if (pure) {
#pragma unroll 4
        for (int jj = 0; jj < JS; ++jj) {
            float4 a = tile[2 * jj + 0];       // broadcast, conflict-free
            float4 b = tile[2 * jj + 1];
#pragma unroll
            for (int k = 0; k < IPT; ++k) {
                float dx = A[k].x - a.x;
                float dy = A[k].y - a.y;
                float dz = A[k].z - a.z;
                float d2p = fmaf(dx, dx, fmaf(dy, dy, fmaf(dz, dz, 1.0f)));
                float rk = __builtin_amdgcn_rcpf(d2p);
                float dot = fmaf(A[k].w, a.w, fmaf(Bn[k].x, b.x, Bn[k].y * b.y));
                acc[k] = fmaf(rk, dot, acc[k]);
            }
        }
#pragma unroll
        for (int k = 0; k < IPT; ++k) acc[k] *= 2.0f;  // interior weight
    } else {
#pragma unroll 4
        for (int jj = 0; jj < JS; ++jj) {
            float4 a = tile[2 * jj + 0];
            float4 b = tile[2 * jj + 1];
            int cj = cj0 + jj;
#pragma unroll
            for (int k = 0; k < IPT; ++k) {
                int d = cj - li[k];
                float w = ((unsigned)(d - 1) < (unsigned)(half - 1)) ? 2.0f
                        : ((d == 0 || d == half) ? 1.0f : 0.0f);
                float dx = A[k].x - a.x;
                float dy = A[k].y - a.y;
                float dz = A[k].z - a.z;
                float d2p = fmaf(dx, dx, fmaf(dy, dy, fmaf(dz, dz, 1.0f)));
                float rk = __builtin_amdgcn_rcpf(d2p);
                float dot = fmaf(A[k].w, a.w, fmaf(Bn[k].x, b.x, Bn[k].y * b.y));
                acc[k] = fmaf(w * rk, dot, acc[k]);
            }
        }
    }

    float s = 0.0f;
#pragma unroll
    for (int k = 0; k < IPT; ++k) s += acc[k];
#pragma unroll
    for (int off = 32; off > 0; off >>= 1) s += __shfl_down(s, off, 64);
    if ((tid & 63) == 0) wsum[tid >> 6] = s;
    __syncthreads();
    if (tid == 0) {
        float t = 0.0f;
#pragma unroll
        for (int w = 0; w < BLK / 64; ++w) t += wsum[w];
        atomicAdd(out, t);
    }
}

extern "C" void kernel_launch(void* const* d_in, const int* in_sizes, int n_in,
                              void* d_out, int out_size, void* d_ws, size_t ws_size,
                              hipStream_t stream) {
    const float* verts = (const float*)d_in[0];   // (V,3) f32
    const float* tnorm = (const float*)d_in[1];   // (M,3) f32
    const float* tcent = (const float*)d_in[2];   // (M,3) f32
    const int*   sidx  = (const int*)d_in[3];     // (N,3) i32

    int M = in_sizes[1] / 3;
    int N = in_sizes[3] / 3;
    int P = N + M;                                // 16384

    float4* comb = (float4*)d_ws;                 // 2 float4/point = 512 KB
    float*  out  = (float*)d_out;

    int bblocks = (P + BLK - 1) / BLK;
    dc_build_combined<<<bblocks, BLK, 0, stream>>>(verts, tnorm, tcent, sidx,
                                                   comb, out, N, M);

    int nslice = (P / 2 + ITILE + JS - 1) / JS;   // 64 for P=16384
    dim3 grid(P / ITILE, nslice);                 // 32 x 64 = 2048 uniform blocks
    dc_pair_energy<<<grid, BLK, 0, stream>>>(comb, out, P);
}